// Round 4
// baseline (618.733 us; speedup 1.0000x reference)
//
#include <hip/hip_runtime.h>
#include <hip/hip_cooperative_groups.h>

namespace cg = cooperative_groups;

#define BB 8
#define NN 2048
#define FF 64
#define HH 32
#define CK 128          // K per chunk
#define NCHK (NN / CK)  // 16 chunks

typedef __attribute__((ext_vector_type(8))) short short8;
typedef __attribute__((ext_vector_type(4))) float floatx4;

static __device__ __forceinline__ float warp_sum64(float v) {
  for (int off = 32; off; off >>= 1) v += __shfl_down(v, off, 64);
  return v;
}

static __device__ __forceinline__ float warp_bsum64(float v) {
  for (int off = 1; off < 64; off <<= 1) v += __shfl_xor(v, off, 64);
  return v;
}

static __device__ __forceinline__ unsigned int f2bf_rne(float f) {
  unsigned int u = __float_as_uint(f);
  return (u + 0x7fffu + ((u >> 16) & 1u)) >> 16;
}
static __device__ __forceinline__ float bf2f(unsigned short s) {
  return __uint_as_float(((unsigned int)s) << 16);
}

#define GLOAD_LDS16(g, l)                                                 \
  __builtin_amdgcn_global_load_lds(                                       \
      (const __attribute__((address_space(1))) unsigned int*)(g),         \
      (__attribute__((address_space(3))) unsigned int*)(l), 16, 0, 0)

// Fused: per row (b,n):
//   d_i = rowsum(a) + add_i ; dm = d^-1/2 ; add_i = (|a_ii| < 1e-7)
//   Abf = bf16(A) (RNE), fused with the mandatory fp32 read (nontemporal:
//   A fp32 is read-once; keep it out of L3 so Abf stays resident there)
//   hst[b][c][n] = bf16( dm_row * sum_k x[row][k] * W1[k][c] )
// Block 0 also zeroes gmax (replaces the hipMemsetAsync dispatch).
__global__ __launch_bounds__(256) void deg_cvt_xw_kernel(
    const float* __restrict__ A, const float* __restrict__ x,
    const float* __restrict__ W1, float* __restrict__ dm,
    float* __restrict__ addf, unsigned short* __restrict__ Abf,
    unsigned short* __restrict__ hst, unsigned int* __restrict__ gmax) {
  __shared__ float wl[FF * HH];  // 8 KB
  __shared__ float xs[4][FF];    // 1 KB
  const int tid = threadIdx.x;
  const int lane = tid & 63;
  const int w = tid >> 6;
  const size_t row = (size_t)blockIdx.x * 4 + w;  // flat b*N + n
  const size_t n = row & (NN - 1);
  const int b = (int)(row >> 11);

  if (blockIdx.x == 0) gmax[tid] = 0;  // BB*HH == 256 entries

  // stage W1 + x rows (consumed after the A pass; loads overlap it)
  for (int k = tid; k < FF * HH; k += 256) wl[k] = W1[k];
  xs[w][lane] = __builtin_nontemporal_load(x + row * FF + lane);

  const float* Ar = A + row * (size_t)NN;
  unsigned int* Abr = (unsigned int*)(Abf + row * (size_t)NN);
  float sum = 0.f;
#pragma unroll
  for (int it = 0; it < 8; ++it) {
    floatx4 v = __builtin_nontemporal_load(
        (const floatx4*)(Ar + it * 256 + lane * 4));
    sum += v.x + v.y + v.z + v.w;
    uint2 p;
    p.x = f2bf_rne(v.x) | (f2bf_rne(v.y) << 16);
    p.y = f2bf_rne(v.z) | (f2bf_rne(v.w) << 16);
    *(uint2*)(Abr + it * 128 + lane * 2) = p;
  }
  sum = warp_bsum64(sum);  // butterfly: all lanes get the row sum
  const float diag = Ar[n];
  const float ad = (fabsf(diag) < 1e-7f) ? 1.f : 0.f;
  const float dmv = 1.f / sqrtf(sum + ad);
  if (lane == 0) {
    dm[row] = dmv;
    addf[row] = ad;
  }

  // xw: lanes (c = lane&31, h = lane>>5) each do half the K reduction
  __syncthreads();  // wl/xs visible (their loads overlapped the A pass)
  const int c = lane & 31, h = lane >> 5;
  float acc = 0.f;
#pragma unroll
  for (int k = 0; k < 32; ++k) {
    const int kk = h * 32 + k;
    acc = fmaf(xs[w][kk], wl[kk * HH + c], acc);
  }
  acc += __shfl_down(acc, 32, 64);
  if (lane < 32)
    hst[((size_t)b * HH + c) * NN + n] = (unsigned short)f2bf_rne(dmv * acc);
}

// One fused GCN layer via MFMA — single-wave blocks, wave-private staging.
// Block = 1 wave = 16-row M-tile x N=32, full K=2048 in 16 chunks of 128.
// Per chunk the wave DMA-stages its own A (16x128) + B (32x128) bf16 into
// its private LDS (triple-buffered) and waits with fine-grained
// s_waitcnt vmcnt(24/12/0) — NO barriers in the K-loop. XOR-granule
// swizzle (granule g of row r at slot g^(r&15)) keeps ds_read_b128
// fragment reads ~conflict-free while the DMA lane map stays contiguous.
// hst_next is written with AGENT-scope atomic stores (write-through to the
// coherence point) so a following in-kernel grid.sync'd phase reads fresh
// data regardless of XCD L2 write-back behavior. (~1 MB/layer — negligible.)
static __device__ __forceinline__ void layer_phase(
    unsigned char (*smem)[12288],
    const unsigned short* __restrict__ Abf,
    const unsigned short* __restrict__ hst_in,
    const float* __restrict__ dm, const float* __restrict__ addf,
    const float* __restrict__ bias, const float* __restrict__ Wn,
    unsigned short* __restrict__ hst_next, unsigned int* __restrict__ gmax,
    const int do_pool, const int b, const int mrow0, const int q,
    const int l15) {
  const unsigned short* aSrc[4];
  const unsigned short* bSrc[8];
#pragma unroll
  for (int i = 0; i < 4; ++i) {
    const int r = i * 4 + q;  // 0..15
    const int gl = l15 ^ r;
    aSrc[i] = Abf + ((size_t)(b * NN + mrow0 + r)) * NN + gl * 8;
  }
#pragma unroll
  for (int i = 0; i < 8; ++i) {
    const int r = i * 4 + q;  // 0..31
    const int gl = l15 ^ (r & 15);
    bSrc[i] = hst_in + ((size_t)(b * HH + r)) * NN + gl * 8;
  }

#define ISSUE(buf)                                                        \
  do {                                                                    \
    _Pragma("unroll") for (int i = 0; i < 4; ++i) {                       \
      GLOAD_LDS16(aSrc[i], &smem[buf][i * 1024]);                         \
      aSrc[i] += CK;                                                      \
    }                                                                     \
    _Pragma("unroll") for (int i = 0; i < 8; ++i) {                       \
      GLOAD_LDS16(bSrc[i], &smem[buf][4096 + i * 1024]);                  \
      bSrc[i] += CK;                                                      \
    }                                                                     \
  } while (0)

  floatx4 acc0 = {0.f, 0.f, 0.f, 0.f};  // cols l15
  floatx4 acc1 = {0.f, 0.f, 0.f, 0.f};  // cols 16+l15

  ISSUE(0);
  ISSUE(1);
#pragma unroll
  for (int c = 0; c < NCHK; ++c) {
    if (c + 2 < NCHK) ISSUE((c + 2) % 3);
    if (c <= NCHK - 3) {
      asm volatile("s_waitcnt vmcnt(24)" ::: "memory");  // c+1,c+2 in flight
    } else if (c == NCHK - 2) {
      asm volatile("s_waitcnt vmcnt(12)" ::: "memory");  // c+1 in flight
    } else {
      asm volatile("s_waitcnt vmcnt(0)" ::: "memory");
    }
    const unsigned char* Ab = smem[c % 3];
    const unsigned char* Bb = smem[c % 3] + 4096;
#pragma unroll
    for (int ks = 0; ks < 4; ++ks) {
      const int go = (((ks * 4 + q) ^ l15) * 16);
      short8 af = *(const short8*)(Ab + l15 * 256 + go);
      short8 b0 = *(const short8*)(Bb + l15 * 256 + go);
      short8 b1 = *(const short8*)(Bb + 4096 + l15 * 256 + go);
      acc0 = __builtin_amdgcn_mfma_f32_16x16x32_bf16(af, b0, acc0, 0, 0, 0);
      acc1 = __builtin_amdgcn_mfma_f32_16x16x32_bf16(af, b1, acc1, 0, 0, 0);
    }
  }
#undef ISSUE

  // --- epilogue: h = relu(dm*(acc + add*hsin) + bias) ---
  const float4 dmq = *(const float4*)(dm + b * NN + mrow0 + q * 4);
  const float4 adq = *(const float4*)(addf + b * NN + mrow0 + q * 4);
  const ushort4 hv0 =
      *(const ushort4*)(hst_in + ((size_t)b * HH + l15) * NN + mrow0 + q * 4);
  const ushort4 hv1 =
      *(const ushort4*)(hst_in + ((size_t)b * HH + 16 + l15) * NN + mrow0 + q * 4);
  float h0[4], h1[4];
#pragma unroll
  for (int r = 0; r < 4; ++r) {
    const float dmv = ((const float*)&dmq)[r];
    const float adv = ((const float*)&adq)[r];
    const float hs0 = bf2f(((const unsigned short*)&hv0)[r]);
    const float hs1 = bf2f(((const unsigned short*)&hv1)[r]);
    h0[r] = fmaxf(fmaf(dmv, acc0[r] + adv * hs0, bias[l15]), 0.f);
    h1[r] = fmaxf(fmaf(dmv, acc1[r] + adv * hs1, bias[16 + l15]), 0.f);
  }

  if (do_pool) {
    float m0 = fmaxf(fmaxf(h0[0], h0[1]), fmaxf(h0[2], h0[3]));
    float m1 = fmaxf(fmaxf(h1[0], h1[1]), fmaxf(h1[2], h1[3]));
    m0 = fmaxf(m0, __shfl_xor(m0, 16, 64));
    m0 = fmaxf(m0, __shfl_xor(m0, 32, 64));
    m1 = fmaxf(m1, __shfl_xor(m1, 16, 64));
    m1 = fmaxf(m1, __shfl_xor(m1, 32, 64));
    if (q == 0) {
      atomicMax(&gmax[b * HH + l15], __float_as_uint(m0));
      atomicMax(&gmax[b * HH + 16 + l15], __float_as_uint(m1));
    }
  } else {
    // transpose h through LDS (overlays staging buf 0 — K-loop done, drained)
    float* hb = (float*)&smem[0][0];  // [16][33]
    __syncthreads();  // single wave: cheap; orders overlay reuse
#pragma unroll
    for (int r = 0; r < 4; ++r) {
      const int row = q * 4 + r;
      hb[row * 33 + l15] = h0[r];
      hb[row * 33 + 16 + l15] = h1[r];
    }
    __syncthreads();
    unsigned short o0[4], o1[4];
#pragma unroll
    for (int r = 0; r < 4; ++r) {
      const int row = q * 4 + r;
      const int rg = b * NN + mrow0 + row;
      float s0 = 0.f, s1 = 0.f;
#pragma unroll
      for (int k = 0; k < HH; ++k) {
        const float hv = hb[row * 33 + k];
        s0 = fmaf(hv, Wn[k * HH + l15], s0);
        s1 = fmaf(hv, Wn[k * HH + 16 + l15], s1);
      }
      const float dmv = dm[rg];
      o0[r] = (unsigned short)f2bf_rne(dmv * s0);
      o1[r] = (unsigned short)f2bf_rne(dmv * s1);
    }
    // AGENT-scope release stores: data reaches the coherence point at the
    // store itself — consumers after grid.sync read fresh lines (first
    // touch per consumer XCD, since L2s are flushed at dispatch launch).
    unsigned long long v0, v1;
    __builtin_memcpy(&v0, o0, 8);
    __builtin_memcpy(&v1, o1, 8);
    __hip_atomic_store(
        (unsigned long long*)(hst_next + ((size_t)b * HH + l15) * NN + mrow0 + q * 4),
        v0, __ATOMIC_RELEASE, __HIP_MEMORY_SCOPE_AGENT);
    __hip_atomic_store(
        (unsigned long long*)(hst_next + ((size_t)b * HH + 16 + l15) * NN + mrow0 + q * 4),
        v1, __ATOMIC_RELEASE, __HIP_MEMORY_SCOPE_AGENT);
  }
}

// All 3 GCN layers + pool + MLP head in ONE cooperative dispatch.
// Grid = 1024 blocks x 64 thr = 4 blocks/CU (36 KB LDS) x 256 CU.
// grid.sync() orders execution; coherence is carried by the agent-scope
// atomic stores in layer_phase (see above), not by fence lowering.
__global__ __launch_bounds__(64) void fused_layers_kernel(
    const unsigned short* __restrict__ Abf,
    const unsigned short* __restrict__ hst_a,
    unsigned short* __restrict__ hst_b, unsigned short* __restrict__ hst_c,
    const float* __restrict__ dm, const float* __restrict__ addf,
    const float* __restrict__ b1, const float* __restrict__ W2,
    const float* __restrict__ b2, const float* __restrict__ W3,
    const float* __restrict__ b3, unsigned int* __restrict__ gmax,
    const float* __restrict__ Wf1, const float* __restrict__ bf1,
    const float* __restrict__ Wf2, const float* __restrict__ bf2,
    float* __restrict__ out) {
  __shared__ __align__(16) unsigned char smem[3][12288];  // 36 KB
  const int tid = threadIdx.x;      // 0..63 (one wave)
  const int mb = blockIdx.x & 127;  // 128 M-tiles of 16 rows
  const int b = blockIdx.x >> 7;
  const int mrow0 = mb * 16;
  const int q = tid >> 4;  // 0..3
  const int l15 = tid & 15;
  cg::grid_group grid = cg::this_grid();

  layer_phase(smem, Abf, hst_a, dm, addf, b1, W2, hst_b, nullptr, 0, b, mrow0,
              q, l15);
  grid.sync();
  layer_phase(smem, Abf, hst_b, dm, addf, b2, W3, hst_c, nullptr, 0, b, mrow0,
              q, l15);
  grid.sync();
  layer_phase(smem, Abf, hst_c, dm, addf, b3, nullptr, nullptr, gmax, 1, b,
              mrow0, q, l15);
  grid.sync();

  // --- head: out[b] = (relu(g @ Wf1 + bf1)) @ Wf2 + bf2 ; block 0 only ---
  if (blockIdx.x == 0) {
#pragma unroll
    for (int bb = 0; bb < BB; ++bb) {
      float acc = bf1[tid];
#pragma unroll
      for (int c = 0; c < HH; ++c) {
        const unsigned int gv = __hip_atomic_load(
            &gmax[bb * HH + c], __ATOMIC_RELAXED, __HIP_MEMORY_SCOPE_AGENT);
        acc = fmaf(__uint_as_float(gv), Wf1[c * (2 * HH) + tid], acc);
      }
      acc = fmaxf(acc, 0.f);
      float v = acc * Wf2[tid];
      v = warp_sum64(v);
      if (tid == 0) out[bb] = v + bf2[0];
    }
  }
}

// ---- fallback path (separate dispatches, proven-correct coherence) ----
__global__ __launch_bounds__(64) void layer_kernel(
    const unsigned short* __restrict__ Abf,
    const unsigned short* __restrict__ hst_in, const float* __restrict__ dm,
    const float* __restrict__ addf, const float* __restrict__ bias,
    const float* __restrict__ Wn, unsigned short* __restrict__ hst_next,
    unsigned int* __restrict__ gmax, const int do_pool) {
  __shared__ __align__(16) unsigned char smem[3][12288];
  const int tid = threadIdx.x;
  const int mb = blockIdx.x & 127;
  const int b = blockIdx.x >> 7;
  layer_phase(smem, Abf, hst_in, dm, addf, bias, Wn, hst_next, gmax, do_pool,
              b, mb * 16, tid >> 4, tid & 15);
}

__global__ __launch_bounds__(64) void head_kernel(const unsigned int* __restrict__ gmax,
                                                  const float* __restrict__ Wf1,
                                                  const float* __restrict__ bf1,
                                                  const float* __restrict__ Wf2,
                                                  const float* __restrict__ bf2,
                                                  float* __restrict__ out) {
  const int b = blockIdx.x;
  const int t = threadIdx.x;
  float acc = bf1[t];
#pragma unroll
  for (int c = 0; c < HH; ++c)
    acc = fmaf(__uint_as_float(gmax[b * HH + c]), Wf1[c * (2 * HH) + t], acc);
  acc = fmaxf(acc, 0.f);
  float v = acc * Wf2[t];
  v = warp_sum64(v);
  if (t == 0) out[b] = v + bf2[0];
}

extern "C" void kernel_launch(void* const* d_in, const int* in_sizes, int n_in,
                              void* d_out, int out_size, void* d_ws, size_t ws_size,
                              hipStream_t stream) {
  const float* x   = (const float*)d_in[0];
  const float* a   = (const float*)d_in[1];
  const float* W1  = (const float*)d_in[2];
  const float* b1  = (const float*)d_in[3];
  const float* W2  = (const float*)d_in[4];
  const float* b2  = (const float*)d_in[5];
  const float* W3  = (const float*)d_in[6];
  const float* b3  = (const float*)d_in[7];
  const float* Wf1 = (const float*)d_in[8];
  const float* bf1 = (const float*)d_in[9];
  const float* Wf2 = (const float*)d_in[10];
  const float* bf2 = (const float*)d_in[11];
  float* out = (float*)d_out;

  float* ws = (float*)d_ws;
  const size_t BN = (size_t)BB * NN;  // 16384
  float* dm   = ws;                                       // 16384 f
  float* addf = dm + BN;                                  // 16384 f
  unsigned int* gmax = (unsigned int*)(addf + BN);        // 256 u32
  unsigned short* hst_a = (unsigned short*)(gmax + 256);  // 1 MB
  unsigned short* hst_b = hst_a + BN * HH;                // 1 MB
  unsigned short* hst_c = hst_b + BN * HH;                // 1 MB
  unsigned short* Abf = hst_c + BN * HH;                  // 67 MB bf16 A
  // total ws use ~70.5 MB

  deg_cvt_xw_kernel<<<BN / 4, 256, 0, stream>>>(a, x, W1, dm, addf, Abf, hst_a,
                                                gmax);

  void* args[] = {&Abf, &hst_a, &hst_b, &hst_c, &dm,  &addf,
                  &b1,  &W2,    &b2,    &W3,    &b3,  &gmax,
                  &Wf1, &bf1,   &Wf2,   &bf2,   &out};
  hipError_t cerr = hipLaunchCooperativeKernel((void*)fused_layers_kernel,
                                               dim3(BB * 128), dim3(64), args,
                                               0, stream);
  if (cerr != hipSuccess) {
    (void)hipGetLastError();  // clear error state
    layer_kernel<<<BB * 128, 64, 0, stream>>>(Abf, hst_a, dm, addf, b1, W2,
                                              hst_b, nullptr, 0);
    layer_kernel<<<BB * 128, 64, 0, stream>>>(Abf, hst_b, dm, addf, b2, W3,
                                              hst_c, nullptr, 0);
    layer_kernel<<<BB * 128, 64, 0, stream>>>(Abf, hst_c, dm, addf, b3,
                                              nullptr, nullptr, gmax, 1);
    head_kernel<<<BB, 64, 0, stream>>>(gmax, Wf1, bf1, Wf2, bf2, out);
  }
}

// Round 5
// 284.725 us; speedup vs baseline: 2.1731x; 2.1731x over previous
//
#include <hip/hip_runtime.h>

#define BB 8
#define NN 2048
#define FF 64
#define HH 32
#define CK 128          // K per chunk
#define NCHK (NN / CK)  // 16 chunks

typedef __attribute__((ext_vector_type(8))) short short8;
typedef __attribute__((ext_vector_type(4))) float floatx4;

static __device__ __forceinline__ float warp_sum64(float v) {
  for (int off = 32; off; off >>= 1) v += __shfl_down(v, off, 64);
  return v;
}

static __device__ __forceinline__ float warp_bsum64(float v) {
  for (int off = 1; off < 64; off <<= 1) v += __shfl_xor(v, off, 64);
  return v;
}

static __device__ __forceinline__ unsigned int f2bf_rne(float f) {
  unsigned int u = __float_as_uint(f);
  return (u + 0x7fffu + ((u >> 16) & 1u)) >> 16;
}
static __device__ __forceinline__ float bf2f(unsigned short s) {
  return __uint_as_float(((unsigned int)s) << 16);
}

#define GLOAD_LDS16(g, l)                                                 \
  __builtin_amdgcn_global_load_lds(                                       \
      (const __attribute__((address_space(1))) unsigned int*)(g),         \
      (__attribute__((address_space(3))) unsigned int*)(l), 16, 0, 0)

// Fused: per row (b,n):
//   d_i = rowsum(a) + add_i ; dm = d^-1/2 ; add_i = (|a_ii| < 1e-7)
//   Abf = bf16(A) (RNE), fused with the mandatory fp32 read (nontemporal:
//   A fp32 is read-once; keep it out of L3 so Abf stays resident there)
//   hst[b][c][n] = bf16( dm_row * sum_k x[row][k] * W1[k][c] )
// Block 0 also zeroes gmax + the done counter (no hipMemsetAsync needed).
__global__ __launch_bounds__(256) void deg_cvt_xw_kernel(
    const float* __restrict__ A, const float* __restrict__ x,
    const float* __restrict__ W1, float* __restrict__ dm,
    float* __restrict__ addf, unsigned short* __restrict__ Abf,
    unsigned short* __restrict__ hst, unsigned int* __restrict__ gmax,
    unsigned int* __restrict__ donecnt) {
  __shared__ float wl[FF * HH];  // 8 KB
  __shared__ float xs[4][FF];    // 1 KB
  const int tid = threadIdx.x;
  const int lane = tid & 63;
  const int w = tid >> 6;
  const size_t row = (size_t)blockIdx.x * 4 + w;  // flat b*N + n
  const size_t n = row & (NN - 1);
  const int b = (int)(row >> 11);

  if (blockIdx.x == 0) {
    gmax[tid] = 0;  // BB*HH == 256 entries
    if (tid == 0) donecnt[0] = 0;
  }

  // stage W1 + x rows (consumed after the A pass; loads overlap it)
  for (int k = tid; k < FF * HH; k += 256) wl[k] = W1[k];
  xs[w][lane] = __builtin_nontemporal_load(x + row * FF + lane);

  const float* Ar = A + row * (size_t)NN;
  unsigned int* Abr = (unsigned int*)(Abf + row * (size_t)NN);
  float sum = 0.f;
#pragma unroll
  for (int it = 0; it < 4; ++it) {
    const float* p = Ar + it * 512 + lane * 8;
    floatx4 v0 = __builtin_nontemporal_load((const floatx4*)p);
    floatx4 v1 = __builtin_nontemporal_load((const floatx4*)(p + 4));
    sum += v0.x + v0.y + v0.z + v0.w + v1.x + v1.y + v1.z + v1.w;
    uint4 pk;
    pk.x = f2bf_rne(v0.x) | (f2bf_rne(v0.y) << 16);
    pk.y = f2bf_rne(v0.z) | (f2bf_rne(v0.w) << 16);
    pk.z = f2bf_rne(v1.x) | (f2bf_rne(v1.y) << 16);
    pk.w = f2bf_rne(v1.z) | (f2bf_rne(v1.w) << 16);
    *(uint4*)(Abr + it * 256 + lane * 4) = pk;
  }
  sum = warp_bsum64(sum);  // butterfly: all lanes get the row sum
  const float diag = Ar[n];
  const float ad = (fabsf(diag) < 1e-7f) ? 1.f : 0.f;
  const float dmv = 1.f / sqrtf(sum + ad);
  if (lane == 0) {
    dm[row] = dmv;
    addf[row] = ad;
  }

  // xw: lanes (c = lane&31, h = lane>>5) each do half the K reduction
  __syncthreads();  // wl/xs visible (their loads overlapped the A pass)
  const int c = lane & 31, h = lane >> 5;
  float acc = 0.f;
#pragma unroll
  for (int k = 0; k < 32; ++k) {
    const int kk = h * 32 + k;
    acc = fmaf(xs[w][kk], wl[kk * HH + c], acc);
  }
  acc += __shfl_down(acc, 32, 64);
  if (lane < 32)
    hst[((size_t)b * HH + c) * NN + n] = (unsigned short)f2bf_rne(dmv * acc);
}

// One fused GCN layer via MFMA — single-wave blocks, wave-private staging.
// Block = 1 wave = 16-row M-tile x N=32, full K=2048 in 16 chunks of 128.
// Per chunk the wave DMA-stages its own A (16x128) + B (32x128) bf16 into
// its private LDS (triple-buffered) and waits with fine-grained
// s_waitcnt vmcnt(24/12/0) — NO barriers in the K-loop. XOR-granule
// swizzle (granule g of row r at slot g^(r&15)) keeps ds_read_b128
// fragment reads ~conflict-free while the DMA lane map stays contiguous.
// Epilogue consumes acc (C layout: row=q*4+reg, col=lane&15) in-wave.
// In the pool variant, the LAST block to finish (device-scope ticket)
// also computes the MLP head — folds the head dispatch away.
__global__ __launch_bounds__(64) void layer_kernel(
    const unsigned short* __restrict__ Abf,
    const unsigned short* __restrict__ hst_in, const float* __restrict__ dm,
    const float* __restrict__ addf, const float* __restrict__ bias,
    const float* __restrict__ Wn, unsigned short* __restrict__ hst_next,
    unsigned int* __restrict__ gmax, unsigned int* __restrict__ donecnt,
    const float* __restrict__ Wf1, const float* __restrict__ bf1,
    const float* __restrict__ Wf2, const float* __restrict__ bf2,
    float* __restrict__ out, const int do_pool) {
  __shared__ __align__(16) unsigned char smem[3][12288];  // A 4KB + B 8KB per buf

  const int tid = threadIdx.x;      // 0..63 (one wave)
  const int mb = blockIdx.x & 127;  // 128 M-tiles of 16 rows
  const int b = blockIdx.x >> 7;
  const int mrow0 = mb * 16;
  const int q = tid >> 4;           // 0..3
  const int l15 = tid & 15;

  // --- DMA source pointers (advance by CK per issued chunk) ---
  // Issue i writes LDS bytes [i*1024, i*1024+1024): row r=i*4+q, slot gd=l15,
  // which must hold global granule gl = gd ^ (r&15).
  const unsigned short* aSrc[4];
  const unsigned short* bSrc[8];
#pragma unroll
  for (int i = 0; i < 4; ++i) {
    const int r = i * 4 + q;  // 0..15
    const int gl = l15 ^ r;
    aSrc[i] = Abf + ((size_t)(b * NN + mrow0 + r)) * NN + gl * 8;
  }
#pragma unroll
  for (int i = 0; i < 8; ++i) {
    const int r = i * 4 + q;  // 0..31
    const int gl = l15 ^ (r & 15);
    bSrc[i] = hst_in + ((size_t)(b * HH + r)) * NN + gl * 8;
  }

#define ISSUE(buf)                                                        \
  do {                                                                    \
    _Pragma("unroll") for (int i = 0; i < 4; ++i) {                       \
      GLOAD_LDS16(aSrc[i], &smem[buf][i * 1024]);                         \
      aSrc[i] += CK;                                                      \
    }                                                                     \
    _Pragma("unroll") for (int i = 0; i < 8; ++i) {                       \
      GLOAD_LDS16(bSrc[i], &smem[buf][4096 + i * 1024]);                  \
      bSrc[i] += CK;                                                      \
    }                                                                     \
  } while (0)

  floatx4 acc0 = {0.f, 0.f, 0.f, 0.f};  // cols l15
  floatx4 acc1 = {0.f, 0.f, 0.f, 0.f};  // cols 16+l15

  ISSUE(0);
  ISSUE(1);
#pragma unroll
  for (int c = 0; c < NCHK; ++c) {
    if (c + 2 < NCHK) ISSUE((c + 2) % 3);
    if (c <= NCHK - 3) {
      asm volatile("s_waitcnt vmcnt(24)" ::: "memory");  // c+1,c+2 in flight
    } else if (c == NCHK - 2) {
      asm volatile("s_waitcnt vmcnt(12)" ::: "memory");  // c+1 in flight
    } else {
      asm volatile("s_waitcnt vmcnt(0)" ::: "memory");
    }
    const unsigned char* Ab = smem[c % 3];
    const unsigned char* Bb = smem[c % 3] + 4096;
#pragma unroll
    for (int ks = 0; ks < 4; ++ks) {
      const int go = (((ks * 4 + q) ^ l15) * 16);
      short8 af = *(const short8*)(Ab + l15 * 256 + go);
      short8 b0 = *(const short8*)(Bb + l15 * 256 + go);
      short8 b1 = *(const short8*)(Bb + 4096 + l15 * 256 + go);
      acc0 = __builtin_amdgcn_mfma_f32_16x16x32_bf16(af, b0, acc0, 0, 0, 0);
      acc1 = __builtin_amdgcn_mfma_f32_16x16x32_bf16(af, b1, acc1, 0, 0, 0);
    }
  }
#undef ISSUE

  // --- epilogue: h = relu(dm*(acc + add*hsin) + bias) ---
  // rows q*4..q*4+3 are consecutive -> vector loads for dm/addf/hst_in
  const float4 dmq = *(const float4*)(dm + b * NN + mrow0 + q * 4);
  const float4 adq = *(const float4*)(addf + b * NN + mrow0 + q * 4);
  const ushort4 hv0 =
      *(const ushort4*)(hst_in + ((size_t)b * HH + l15) * NN + mrow0 + q * 4);
  const ushort4 hv1 =
      *(const ushort4*)(hst_in + ((size_t)b * HH + 16 + l15) * NN + mrow0 + q * 4);
  float h0[4], h1[4];
#pragma unroll
  for (int r = 0; r < 4; ++r) {
    const float dmv = ((const float*)&dmq)[r];
    const float adv = ((const float*)&adq)[r];
    const float hs0 = bf2f(((const unsigned short*)&hv0)[r]);
    const float hs1 = bf2f(((const unsigned short*)&hv1)[r]);
    h0[r] = fmaxf(fmaf(dmv, acc0[r] + adv * hs0, bias[l15]), 0.f);
    h1[r] = fmaxf(fmaf(dmv, acc1[r] + adv * hs1, bias[16 + l15]), 0.f);
  }

  if (do_pool) {
    float m0 = fmaxf(fmaxf(h0[0], h0[1]), fmaxf(h0[2], h0[3]));
    float m1 = fmaxf(fmaxf(h1[0], h1[1]), fmaxf(h1[2], h1[3]));
    m0 = fmaxf(m0, __shfl_xor(m0, 16, 64));
    m0 = fmaxf(m0, __shfl_xor(m0, 32, 64));
    m1 = fmaxf(m1, __shfl_xor(m1, 16, 64));
    m1 = fmaxf(m1, __shfl_xor(m1, 32, 64));
    if (q == 0) {
      atomicMax(&gmax[b * HH + l15], __float_as_uint(m0));
      atomicMax(&gmax[b * HH + 16 + l15], __float_as_uint(m1));
    }
    // ---- last-block ticket: the final block computes the MLP head ----
    __threadfence();  // release: our gmax atomics reach coherence point
    unsigned int ticket = 0;
    if (tid == 0) ticket = atomicAdd(donecnt, 1);
    ticket = __shfl(ticket, 0, 64);
    if (ticket == gridDim.x - 1) {
      __threadfence();  // acquire side
#pragma unroll
      for (int bb = 0; bb < BB; ++bb) {
        float acc = bf1[tid];
#pragma unroll
        for (int c = 0; c < HH; ++c) {
          const unsigned int gv = __hip_atomic_load(
              &gmax[bb * HH + c], __ATOMIC_RELAXED, __HIP_MEMORY_SCOPE_AGENT);
          acc = fmaf(__uint_as_float(gv), Wf1[c * (2 * HH) + tid], acc);
        }
        acc = fmaxf(acc, 0.f);
        float v = acc * Wf2[tid];
        v = warp_sum64(v);
        if (tid == 0) out[bb] = v + bf2[0];
      }
    }
  } else {
    // transpose h through LDS (overlays staging buf 0 — K-loop done, drained)
    float* hb = (float*)&smem[0][0];  // [16][33]
    __syncthreads();  // single wave: cheap; orders overlay reuse
#pragma unroll
    for (int r = 0; r < 4; ++r) {
      const int row = q * 4 + r;
      hb[row * 33 + l15] = h0[r];
      hb[row * 33 + 16 + l15] = h1[r];
    }
    __syncthreads();
    unsigned short o0[4], o1[4];
#pragma unroll
    for (int r = 0; r < 4; ++r) {
      const int row = q * 4 + r;
      const int rg = b * NN + mrow0 + row;
      float s0 = 0.f, s1 = 0.f;
#pragma unroll
      for (int k = 0; k < HH; ++k) {
        const float hv = hb[row * 33 + k];
        s0 = fmaf(hv, Wn[k * HH + l15], s0);
        s1 = fmaf(hv, Wn[k * HH + 16 + l15], s1);
      }
      const float dmv = dm[rg];
      o0[r] = (unsigned short)f2bf_rne(dmv * s0);
      o1[r] = (unsigned short)f2bf_rne(dmv * s1);
    }
    // store: o0[r] holds row q*4+r for col l15; rows q*4..q*4+3 are
    // consecutive in hst_next's n-dim -> one ushort4 per col.
    *(ushort4*)(hst_next + ((size_t)b * HH + l15) * NN + mrow0 + q * 4) =
        *(ushort4*)o0;
    *(ushort4*)(hst_next + ((size_t)b * HH + 16 + l15) * NN + mrow0 + q * 4) =
        *(ushort4*)o1;
  }
}

extern "C" void kernel_launch(void* const* d_in, const int* in_sizes, int n_in,
                              void* d_out, int out_size, void* d_ws, size_t ws_size,
                              hipStream_t stream) {
  const float* x   = (const float*)d_in[0];
  const float* a   = (const float*)d_in[1];
  const float* W1  = (const float*)d_in[2];
  const float* b1  = (const float*)d_in[3];
  const float* W2  = (const float*)d_in[4];
  const float* b2  = (const float*)d_in[5];
  const float* W3  = (const float*)d_in[6];
  const float* b3  = (const float*)d_in[7];
  const float* Wf1 = (const float*)d_in[8];
  const float* bf1 = (const float*)d_in[9];
  const float* Wf2 = (const float*)d_in[10];
  const float* bf2 = (const float*)d_in[11];
  float* out = (float*)d_out;

  float* ws = (float*)d_ws;
  const size_t BN = (size_t)BB * NN;  // 16384
  float* dm   = ws;                                       // 16384 f
  float* addf = dm + BN;                                  // 16384 f
  unsigned int* gmax = (unsigned int*)(addf + BN);        // 256 u32
  unsigned int* donecnt = gmax + 256;                     // 1 u32 (+pad 63)
  unsigned short* hst_a = (unsigned short*)(donecnt + 64);  // 1 MB
  unsigned short* hst_b = hst_a + BN * HH;                // 1 MB
  unsigned short* Abf = hst_b + BN * HH;                  // 67 MB bf16 A
  // total ws use ~69.5 MB

  deg_cvt_xw_kernel<<<BN / 4, 256, 0, stream>>>(a, x, W1, dm, addf, Abf, hst_a,
                                                gmax, donecnt);

  layer_kernel<<<BB * 128, 64, 0, stream>>>(Abf, hst_a, dm, addf, b1, W2,
                                            hst_b, nullptr, nullptr, nullptr,
                                            nullptr, nullptr, nullptr, nullptr,
                                            0);
  layer_kernel<<<BB * 128, 64, 0, stream>>>(Abf, hst_b, dm, addf, b2, W3,
                                            hst_a, nullptr, nullptr, nullptr,
                                            nullptr, nullptr, nullptr, nullptr,
                                            0);
  layer_kernel<<<BB * 128, 64, 0, stream>>>(Abf, hst_a, dm, addf, b3, nullptr,
                                            nullptr, gmax, donecnt, Wf1, bf1,
                                            Wf2, bf2, out, 1);
}

// Round 6
// 271.476 us; speedup vs baseline: 2.2791x; 1.0488x over previous
//
#include <hip/hip_runtime.h>

#define BB 8
#define NN 2048
#define FF 64
#define HH 32
#define CK 128          // K per chunk
#define NCHK (NN / CK)  // 16 chunks

typedef __attribute__((ext_vector_type(8))) short short8;
typedef __attribute__((ext_vector_type(4))) float floatx4;

static __device__ __forceinline__ float warp_sum64(float v) {
  for (int off = 32; off; off >>= 1) v += __shfl_down(v, off, 64);
  return v;
}

static __device__ __forceinline__ float warp_bsum64(float v) {
  for (int off = 1; off < 64; off <<= 1) v += __shfl_xor(v, off, 64);
  return v;
}

static __device__ __forceinline__ unsigned int f2bf_rne(float f) {
  unsigned int u = __float_as_uint(f);
  return (u + 0x7fffu + ((u >> 16) & 1u)) >> 16;
}
static __device__ __forceinline__ float bf2f(unsigned short s) {
  return __uint_as_float(((unsigned int)s) << 16);
}

#define GLOAD_LDS16(g, l)                                                 \
  __builtin_amdgcn_global_load_lds(                                       \
      (const __attribute__((address_space(1))) unsigned int*)(g),         \
      (__attribute__((address_space(3))) unsigned int*)(l), 16, 0, 0)

// Fused: per row (b,n):
//   d_i = rowsum(a) + add_i ; dm = d^-1/2 ; add_i = (|a_ii| < 1e-7)
//   Abf = bf16(A) (RNE), fused with the mandatory fp32 read.
//   Loads are one float4/lane — PERFECTLY coalesced (whole cachelines per
//   instruction); do not widen per-lane footprint: nt loads + partial-line
//   use re-fetches the stream (R5 regression, +21us).
//   hst[b][c][n] = bf16( dm_row * sum_k x[row][k] * W1[k][c] )
// Block 0 also zeroes gmax + donecnt (no hipMemsetAsync needed).
__global__ __launch_bounds__(256) void deg_cvt_xw_kernel(
    const float* __restrict__ A, const float* __restrict__ x,
    const float* __restrict__ W1, float* __restrict__ dm,
    float* __restrict__ addf, unsigned short* __restrict__ Abf,
    unsigned short* __restrict__ hst, unsigned int* __restrict__ gmax,
    unsigned int* __restrict__ donecnt) {
  __shared__ float wl[FF * HH];  // 8 KB
  __shared__ float xs[4][FF];    // 1 KB
  const int tid = threadIdx.x;
  const int lane = tid & 63;
  const int w = tid >> 6;
  const size_t row = (size_t)blockIdx.x * 4 + w;  // flat b*N + n
  const size_t n = row & (NN - 1);
  const int b = (int)(row >> 11);

  if (blockIdx.x == 0) {
    gmax[tid] = 0;  // BB*HH == 256 entries
    if (tid == 0) donecnt[0] = 0;
  }

  // stage W1 + x rows (consumed after the A pass; loads overlap it)
  for (int k = tid; k < FF * HH; k += 256) wl[k] = W1[k];
  xs[w][lane] = __builtin_nontemporal_load(x + row * FF + lane);

  const float* Ar = A + row * (size_t)NN;
  unsigned int* Abr = (unsigned int*)(Abf + row * (size_t)NN);
  float sum = 0.f;
#pragma unroll
  for (int it = 0; it < 8; ++it) {
    floatx4 v = __builtin_nontemporal_load(
        (const floatx4*)(Ar + it * 256 + lane * 4));
    sum += v.x + v.y + v.z + v.w;
    uint2 p;
    p.x = f2bf_rne(v.x) | (f2bf_rne(v.y) << 16);
    p.y = f2bf_rne(v.z) | (f2bf_rne(v.w) << 16);
    *(uint2*)(Abr + it * 128 + lane * 2) = p;
  }
  sum = warp_bsum64(sum);  // butterfly: all lanes get the row sum
  const float diag = Ar[n];
  const float ad = (fabsf(diag) < 1e-7f) ? 1.f : 0.f;
  const float dmv = 1.f / sqrtf(sum + ad);
  if (lane == 0) {
    dm[row] = dmv;
    addf[row] = ad;
  }

  // xw: lanes (c = lane&31, h = lane>>5) each do half the K reduction
  __syncthreads();  // wl/xs visible (their loads overlapped the A pass)
  const int c = lane & 31, h = lane >> 5;
  float acc = 0.f;
#pragma unroll
  for (int k = 0; k < 32; ++k) {
    const int kk = h * 32 + k;
    acc = fmaf(xs[w][kk], wl[kk * HH + c], acc);
  }
  acc += __shfl_down(acc, 32, 64);
  if (lane < 32)
    hst[((size_t)b * HH + c) * NN + n] = (unsigned short)f2bf_rne(dmv * acc);
}

// One fused GCN layer via MFMA — single-wave blocks, wave-private staging.
// Block = 1 wave = 16-row M-tile x N=32, full K=2048 in 16 chunks of 128.
// Per chunk the wave DMA-stages its own A (16x128) + B (32x128) bf16 into
// its private LDS (triple-buffered) and waits with fine-grained
// s_waitcnt vmcnt(24/12/0) — NO barriers in the K-loop. XOR-granule
// swizzle (granule g of row r at slot g^(r&15)) keeps ds_read_b128
// fragment reads ~conflict-free while the DMA lane map stays contiguous.
// Epilogue consumes acc (C layout: row=q*4+reg, col=lane&15) in-wave.
// Pool variant: fence-free last-block ticket computes the MLP head.
// All gmax traffic is device-scope atomics (coherence-point ops, never
// cached) so ordering needs only the wave-local s_waitcnt vmcnt(0) between
// a block's maxes and its ticket add — NO __threadfence (no L2 writeback;
// the R5 threadfence was a regression suspect).
__global__ __launch_bounds__(64) void layer_kernel(
    const unsigned short* __restrict__ Abf,
    const unsigned short* __restrict__ hst_in, const float* __restrict__ dm,
    const float* __restrict__ addf, const float* __restrict__ bias,
    const float* __restrict__ Wn, unsigned short* __restrict__ hst_next,
    unsigned int* __restrict__ gmax, unsigned int* __restrict__ donecnt,
    const float* __restrict__ Wf1, const float* __restrict__ bf1,
    const float* __restrict__ Wf2, const float* __restrict__ bf2,
    float* __restrict__ out, const int do_pool) {
  __shared__ __align__(16) unsigned char smem[3][12288];  // A 4KB + B 8KB per buf

  const int tid = threadIdx.x;      // 0..63 (one wave)
  const int mb = blockIdx.x & 127;  // 128 M-tiles of 16 rows
  const int b = blockIdx.x >> 7;
  const int mrow0 = mb * 16;
  const int q = tid >> 4;           // 0..3
  const int l15 = tid & 15;

  // --- DMA source pointers (advance by CK per issued chunk) ---
  // Issue i writes LDS bytes [i*1024, i*1024+1024): row r=i*4+q, slot gd=l15,
  // which must hold global granule gl = gd ^ (r&15).
  const unsigned short* aSrc[4];
  const unsigned short* bSrc[8];
#pragma unroll
  for (int i = 0; i < 4; ++i) {
    const int r = i * 4 + q;  // 0..15
    const int gl = l15 ^ r;
    aSrc[i] = Abf + ((size_t)(b * NN + mrow0 + r)) * NN + gl * 8;
  }
#pragma unroll
  for (int i = 0; i < 8; ++i) {
    const int r = i * 4 + q;  // 0..31
    const int gl = l15 ^ (r & 15);
    bSrc[i] = hst_in + ((size_t)(b * HH + r)) * NN + gl * 8;
  }

#define ISSUE(buf)                                                        \
  do {                                                                    \
    _Pragma("unroll") for (int i = 0; i < 4; ++i) {                       \
      GLOAD_LDS16(aSrc[i], &smem[buf][i * 1024]);                         \
      aSrc[i] += CK;                                                      \
    }                                                                     \
    _Pragma("unroll") for (int i = 0; i < 8; ++i) {                       \
      GLOAD_LDS16(bSrc[i], &smem[buf][4096 + i * 1024]);                  \
      bSrc[i] += CK;                                                      \
    }                                                                     \
  } while (0)

  floatx4 acc0 = {0.f, 0.f, 0.f, 0.f};  // cols l15
  floatx4 acc1 = {0.f, 0.f, 0.f, 0.f};  // cols 16+l15

  ISSUE(0);
  ISSUE(1);
#pragma unroll
  for (int c = 0; c < NCHK; ++c) {
    if (c + 2 < NCHK) ISSUE((c + 2) % 3);
    if (c <= NCHK - 3) {
      asm volatile("s_waitcnt vmcnt(24)" ::: "memory");  // c+1,c+2 in flight
    } else if (c == NCHK - 2) {
      asm volatile("s_waitcnt vmcnt(12)" ::: "memory");  // c+1 in flight
    } else {
      asm volatile("s_waitcnt vmcnt(0)" ::: "memory");
    }
    const unsigned char* Ab = smem[c % 3];
    const unsigned char* Bb = smem[c % 3] + 4096;
#pragma unroll
    for (int ks = 0; ks < 4; ++ks) {
      const int go = (((ks * 4 + q) ^ l15) * 16);
      short8 af = *(const short8*)(Ab + l15 * 256 + go);
      short8 b0 = *(const short8*)(Bb + l15 * 256 + go);
      short8 b1 = *(const short8*)(Bb + 4096 + l15 * 256 + go);
      acc0 = __builtin_amdgcn_mfma_f32_16x16x32_bf16(af, b0, acc0, 0, 0, 0);
      acc1 = __builtin_amdgcn_mfma_f32_16x16x32_bf16(af, b1, acc1, 0, 0, 0);
    }
  }
#undef ISSUE

  // --- epilogue: h = relu(dm*(acc + add*hsin) + bias) ---
  // rows q*4..q*4+3 are consecutive -> vector loads for dm/addf/hst_in
  const float4 dmq = *(const float4*)(dm + b * NN + mrow0 + q * 4);
  const float4 adq = *(const float4*)(addf + b * NN + mrow0 + q * 4);
  const ushort4 hv0 =
      *(const ushort4*)(hst_in + ((size_t)b * HH + l15) * NN + mrow0 + q * 4);
  const ushort4 hv1 =
      *(const ushort4*)(hst_in + ((size_t)b * HH + 16 + l15) * NN + mrow0 + q * 4);
  float h0[4], h1[4];
#pragma unroll
  for (int r = 0; r < 4; ++r) {
    const float dmv = ((const float*)&dmq)[r];
    const float adv = ((const float*)&adq)[r];
    const float hs0 = bf2f(((const unsigned short*)&hv0)[r]);
    const float hs1 = bf2f(((const unsigned short*)&hv1)[r]);
    h0[r] = fmaxf(fmaf(dmv, acc0[r] + adv * hs0, bias[l15]), 0.f);
    h1[r] = fmaxf(fmaf(dmv, acc1[r] + adv * hs1, bias[16 + l15]), 0.f);
  }

  if (do_pool) {
    float m0 = fmaxf(fmaxf(h0[0], h0[1]), fmaxf(h0[2], h0[3]));
    float m1 = fmaxf(fmaxf(h1[0], h1[1]), fmaxf(h1[2], h1[3]));
    m0 = fmaxf(m0, __shfl_xor(m0, 16, 64));
    m0 = fmaxf(m0, __shfl_xor(m0, 32, 64));
    m1 = fmaxf(m1, __shfl_xor(m1, 16, 64));
    m1 = fmaxf(m1, __shfl_xor(m1, 32, 64));
    if (q == 0) {
      atomicMax(&gmax[b * HH + l15], __float_as_uint(m0));
      atomicMax(&gmax[b * HH + 16 + l15], __float_as_uint(m1));
    }
    // Wave-local drain: our atomicMax ops are complete at the coherence
    // point before the ticket add is issued (same wave, vmcnt ordering).
    asm volatile("s_waitcnt vmcnt(0)" ::: "memory");
    unsigned int ticket = 0;
    if (tid == 0) ticket = atomicAdd(donecnt, 1u);
    ticket = (unsigned int)__shfl((int)ticket, 0, 64);
    if (ticket == (unsigned int)(gridDim.x - 1)) {
      // all other blocks' maxes reached the coherence point before their
      // ticket adds; read gmax with agent-scope atomic loads (uncached).
#pragma unroll
      for (int bb = 0; bb < BB; ++bb) {
        float acc = bf1[tid];
#pragma unroll
        for (int c = 0; c < HH; ++c) {
          const unsigned int gv = __hip_atomic_load(
              &gmax[bb * HH + c], __ATOMIC_RELAXED, __HIP_MEMORY_SCOPE_AGENT);
          acc = fmaf(__uint_as_float(gv), Wf1[c * (2 * HH) + tid], acc);
        }
        acc = fmaxf(acc, 0.f);
        float v = acc * Wf2[tid];
        v = warp_sum64(v);
        if (tid == 0) out[bb] = v + bf2[0];
      }
    }
  } else {
    // transpose h through LDS (overlays staging buf 0 — K-loop done, drained)
    float* hb = (float*)&smem[0][0];  // [16][33]
    __syncthreads();  // single wave: cheap; orders overlay reuse
#pragma unroll
    for (int r = 0; r < 4; ++r) {
      const int row = q * 4 + r;
      hb[row * 33 + l15] = h0[r];
      hb[row * 33 + 16 + l15] = h1[r];
    }
    __syncthreads();
    unsigned short o0[4], o1[4];
#pragma unroll
    for (int r = 0; r < 4; ++r) {
      const int row = q * 4 + r;
      const int rg = b * NN + mrow0 + row;
      float s0 = 0.f, s1 = 0.f;
#pragma unroll
      for (int k = 0; k < HH; ++k) {
        const float hv = hb[row * 33 + k];
        s0 = fmaf(hv, Wn[k * HH + l15], s0);
        s1 = fmaf(hv, Wn[k * HH + 16 + l15], s1);
      }
      const float dmv = dm[rg];
      o0[r] = (unsigned short)f2bf_rne(dmv * s0);
      o1[r] = (unsigned short)f2bf_rne(dmv * s1);
    }
    // store: o0[r] holds row q*4+r for col l15; rows q*4..q*4+3 are
    // consecutive in hst_next's n-dim -> one ushort4 per col.
    *(ushort4*)(hst_next + ((size_t)b * HH + l15) * NN + mrow0 + q * 4) =
        *(ushort4*)o0;
    *(ushort4*)(hst_next + ((size_t)b * HH + 16 + l15) * NN + mrow0 + q * 4) =
        *(ushort4*)o1;
  }
}

extern "C" void kernel_launch(void* const* d_in, const int* in_sizes, int n_in,
                              void* d_out, int out_size, void* d_ws, size_t ws_size,
                              hipStream_t stream) {
  const float* x   = (const float*)d_in[0];
  const float* a   = (const float*)d_in[1];
  const float* W1  = (const float*)d_in[2];
  const float* b1  = (const float*)d_in[3];
  const float* W2  = (const float*)d_in[4];
  const float* b2  = (const float*)d_in[5];
  const float* W3  = (const float*)d_in[6];
  const float* b3  = (const float*)d_in[7];
  const float* Wf1 = (const float*)d_in[8];
  const float* bf1 = (const float*)d_in[9];
  const float* Wf2 = (const float*)d_in[10];
  const float* bf2 = (const float*)d_in[11];
  float* out = (float*)d_out;

  float* ws = (float*)d_ws;
  const size_t BN = (size_t)BB * NN;  // 16384
  float* dm   = ws;                                       // 16384 f
  float* addf = dm + BN;                                  // 16384 f
  unsigned int* gmax = (unsigned int*)(addf + BN);        // 256 u32
  unsigned int* donecnt = gmax + 256;                     // 1 u32 (+pad 63)
  unsigned short* hst_a = (unsigned short*)(donecnt + 64);  // 1 MB
  unsigned short* hst_b = hst_a + BN * HH;                // 1 MB
  unsigned short* Abf = hst_b + BN * HH;                  // 67 MB bf16 A
  // total ws use ~69.5 MB

  deg_cvt_xw_kernel<<<BN / 4, 256, 0, stream>>>(a, x, W1, dm, addf, Abf, hst_a,
                                                gmax, donecnt);

  layer_kernel<<<BB * 128, 64, 0, stream>>>(Abf, hst_a, dm, addf, b1, W2,
                                            hst_b, nullptr, nullptr, nullptr,
                                            nullptr, nullptr, nullptr, nullptr,
                                            0);
  layer_kernel<<<BB * 128, 64, 0, stream>>>(Abf, hst_b, dm, addf, b2, W3,
                                            hst_a, nullptr, nullptr, nullptr,
                                            nullptr, nullptr, nullptr, nullptr,
                                            0);
  layer_kernel<<<BB * 128, 64, 0, stream>>>(Abf, hst_a, dm, addf, b3, nullptr,
                                            nullptr, gmax, donecnt, Wf1, bf1,
                                            Wf2, bf2, out, 1);
}

// Round 7
// 257.007 us; speedup vs baseline: 2.4075x; 1.0563x over previous
//
#include <hip/hip_runtime.h>

#define BB 8
#define NN 2048
#define FF 64
#define HH 32
#define CK 128          // K per chunk
#define NCHK (NN / CK)  // 16 chunks

typedef __attribute__((ext_vector_type(8))) short short8;
typedef __attribute__((ext_vector_type(4))) float floatx4;

static __device__ __forceinline__ float warp_sum64(float v) {
  for (int off = 32; off; off >>= 1) v += __shfl_down(v, off, 64);
  return v;
}

static __device__ __forceinline__ float warp_bsum64(float v) {
  for (int off = 1; off < 64; off <<= 1) v += __shfl_xor(v, off, 64);
  return v;
}

static __device__ __forceinline__ unsigned int f2bf_rne(float f) {
  unsigned int u = __float_as_uint(f);
  return (u + 0x7fffu + ((u >> 16) & 1u)) >> 16;
}
static __device__ __forceinline__ float bf2f(unsigned short s) {
  return __uint_as_float(((unsigned int)s) << 16);
}

#define GLOAD_LDS16(g, l)                                                 \
  __builtin_amdgcn_global_load_lds(                                       \
      (const __attribute__((address_space(1))) unsigned int*)(g),         \
      (__attribute__((address_space(3))) unsigned int*)(l), 16, 0, 0)

// Fused: per row (b,n):
//   d_i = rowsum(a) + add_i ; dm = d^-1/2 ; add_i = (|a_ii| < 1e-7)
//   Abf = bf16(A) (RNE), fused with the mandatory fp32 read.
//   Loads are one float4/lane — PERFECTLY coalesced; do not widen per-lane
//   footprint (R5 regression: nt + partial-line use re-fetches the stream).
//   hst[b][c][n] = bf16( dm_row * sum_k x[row][k] * W1[k][c] )
// Block 0 also zeroes gmax (replaces the hipMemsetAsync dispatch).
__global__ __launch_bounds__(256) void deg_cvt_xw_kernel(
    const float* __restrict__ A, const float* __restrict__ x,
    const float* __restrict__ W1, float* __restrict__ dm,
    float* __restrict__ addf, unsigned short* __restrict__ Abf,
    unsigned short* __restrict__ hst, unsigned int* __restrict__ gmax) {
  __shared__ float wl[FF * HH];  // 8 KB
  __shared__ float xs[4][FF];    // 1 KB
  const int tid = threadIdx.x;
  const int lane = tid & 63;
  const int w = tid >> 6;
  const size_t row = (size_t)blockIdx.x * 4 + w;  // flat b*N + n
  const size_t n = row & (NN - 1);
  const int b = (int)(row >> 11);

  if (blockIdx.x == 0) gmax[tid] = 0;  // BB*HH == 256 entries

  // stage W1 + x rows (consumed after the A pass; loads overlap it)
  for (int k = tid; k < FF * HH; k += 256) wl[k] = W1[k];
  xs[w][lane] = __builtin_nontemporal_load(x + row * FF + lane);

  const float* Ar = A + row * (size_t)NN;
  unsigned int* Abr = (unsigned int*)(Abf + row * (size_t)NN);
  float sum = 0.f;
#pragma unroll
  for (int it = 0; it < 8; ++it) {
    floatx4 v = __builtin_nontemporal_load(
        (const floatx4*)(Ar + it * 256 + lane * 4));
    sum += v.x + v.y + v.z + v.w;
    uint2 p;
    p.x = f2bf_rne(v.x) | (f2bf_rne(v.y) << 16);
    p.y = f2bf_rne(v.z) | (f2bf_rne(v.w) << 16);
    *(uint2*)(Abr + it * 128 + lane * 2) = p;
  }
  sum = warp_bsum64(sum);  // butterfly: all lanes get the row sum
  const float diag = Ar[n];
  const float ad = (fabsf(diag) < 1e-7f) ? 1.f : 0.f;
  const float dmv = 1.f / sqrtf(sum + ad);
  if (lane == 0) {
    dm[row] = dmv;
    addf[row] = ad;
  }

  // xw: lanes (c = lane&31, h = lane>>5) each do half the K reduction
  __syncthreads();  // wl/xs visible (their loads overlapped the A pass)
  const int c = lane & 31, h = lane >> 5;
  float acc = 0.f;
#pragma unroll
  for (int k = 0; k < 32; ++k) {
    const int kk = h * 32 + k;
    acc = fmaf(xs[w][kk], wl[kk * HH + c], acc);
  }
  acc += __shfl_down(acc, 32, 64);
  if (lane < 32)
    hst[((size_t)b * HH + c) * NN + n] = (unsigned short)f2bf_rne(dmv * acc);
}

// One fused GCN layer via MFMA — single-wave blocks, wave-private staging.
// Block = 1 wave = 32-row M-tile x N=32, full K=2048 in 16 chunks of 128.
// TWO 16-row sub-tiles share each staged B chunk: per chunk A 8KB + B 8KB
// (16 DMA issues) feed 16 MFMAs — vs the old 16-row tile's 12KB/8 MFMA.
// Cuts total staging traffic 33% (B = hst is the operand reused by every
// tile of a batch). Triple-buffered, fine-grained s_waitcnt vmcnt(32/16/0),
// NO barriers in the K-loop. XOR-granule swizzle (granule g of row r at
// slot g^(r&15)) keeps ds_read_b128 reads ~conflict-free while the DMA
// lane map stays contiguous. C layout: row=m*16+q*4+reg, col=j*16+(lane&15).
__global__ __launch_bounds__(64) void layer_kernel(
    const unsigned short* __restrict__ Abf,
    const unsigned short* __restrict__ hst_in, const float* __restrict__ dm,
    const float* __restrict__ addf, const float* __restrict__ bias,
    const float* __restrict__ Wn, unsigned short* __restrict__ hst_next,
    unsigned int* __restrict__ gmax, const int do_pool) {
  __shared__ __align__(16) unsigned char smem[3][16384];  // A 8KB + B 8KB per buf

  const int tid = threadIdx.x;     // 0..63 (one wave)
  const int mb = blockIdx.x & 63;  // 64 M-tiles of 32 rows
  const int b = blockIdx.x >> 6;
  const int mrow0 = mb * 32;
  const int q = tid >> 4;          // 0..3
  const int l15 = tid & 15;

  // --- DMA source pointers (advance by CK per issued chunk) ---
  // Issue i writes LDS bytes [i*1024, i*1024+1024): row r=i*4+q lands at
  // byte r*256 + gd*16 with slot gd=l15, which must hold global granule
  // gl = gd ^ (r&15).
  const unsigned short* aSrc[8];
  const unsigned short* bSrc[8];
#pragma unroll
  for (int i = 0; i < 8; ++i) {
    const int r = i * 4 + q;  // 0..31
    const int gl = l15 ^ (r & 15);
    aSrc[i] = Abf + ((size_t)(b * NN + mrow0 + r)) * NN + gl * 8;
    bSrc[i] = hst_in + ((size_t)(b * HH + r)) * NN + gl * 8;
  }

#define ISSUE(buf)                                                        \
  do {                                                                    \
    _Pragma("unroll") for (int i = 0; i < 8; ++i) {                       \
      GLOAD_LDS16(aSrc[i], &smem[buf][i * 1024]);                         \
      aSrc[i] += CK;                                                      \
    }                                                                     \
    _Pragma("unroll") for (int i = 0; i < 8; ++i) {                       \
      GLOAD_LDS16(bSrc[i], &smem[buf][8192 + i * 1024]);                  \
      bSrc[i] += CK;                                                      \
    }                                                                     \
  } while (0)

  floatx4 acc[2][2];  // [m sub-tile][n half]; all indices compile-time
#pragma unroll
  for (int m = 0; m < 2; ++m)
#pragma unroll
    for (int j = 0; j < 2; ++j) acc[m][j] = (floatx4){0.f, 0.f, 0.f, 0.f};

  ISSUE(0);
  ISSUE(1);
#pragma unroll
  for (int c = 0; c < NCHK; ++c) {
    if (c + 2 < NCHK) ISSUE((c + 2) % 3);
    if (c <= NCHK - 3) {
      asm volatile("s_waitcnt vmcnt(32)" ::: "memory");  // c+1,c+2 in flight
    } else if (c == NCHK - 2) {
      asm volatile("s_waitcnt vmcnt(16)" ::: "memory");  // c+1 in flight
    } else {
      asm volatile("s_waitcnt vmcnt(0)" ::: "memory");
    }
    const unsigned char* Ab = smem[c % 3];
    const unsigned char* Bb = smem[c % 3] + 8192;
#pragma unroll
    for (int ks = 0; ks < 4; ++ks) {
      const int go = (((ks * 4 + q) ^ l15) * 16);
      short8 a0 = *(const short8*)(Ab + l15 * 256 + go);
      short8 a1 = *(const short8*)(Ab + 4096 + l15 * 256 + go);
      short8 b0 = *(const short8*)(Bb + l15 * 256 + go);
      short8 b1 = *(const short8*)(Bb + 4096 + l15 * 256 + go);
      acc[0][0] = __builtin_amdgcn_mfma_f32_16x16x32_bf16(a0, b0, acc[0][0], 0, 0, 0);
      acc[0][1] = __builtin_amdgcn_mfma_f32_16x16x32_bf16(a0, b1, acc[0][1], 0, 0, 0);
      acc[1][0] = __builtin_amdgcn_mfma_f32_16x16x32_bf16(a1, b0, acc[1][0], 0, 0, 0);
      acc[1][1] = __builtin_amdgcn_mfma_f32_16x16x32_bf16(a1, b1, acc[1][1], 0, 0, 0);
    }
  }
#undef ISSUE

  // --- epilogue: h = relu(dm*(acc + add*hsin) + bias) ---
  // rows m*16+q*4..+3 are consecutive -> vector loads for dm/addf/hst_in
  const int rowb = b * NN + mrow0;
  float4 dmq[2], adq[2];
  ushort4 hv[2][2];  // [m][j]
#pragma unroll
  for (int m = 0; m < 2; ++m) {
    dmq[m] = *(const float4*)(dm + rowb + m * 16 + q * 4);
    adq[m] = *(const float4*)(addf + rowb + m * 16 + q * 4);
    hv[m][0] = *(const ushort4*)(hst_in + ((size_t)b * HH + l15) * NN + mrow0 +
                                 m * 16 + q * 4);
    hv[m][1] = *(const ushort4*)(hst_in + ((size_t)b * HH + 16 + l15) * NN +
                                 mrow0 + m * 16 + q * 4);
  }
  float h[2][2][4];
#pragma unroll
  for (int m = 0; m < 2; ++m)
#pragma unroll
    for (int r = 0; r < 4; ++r) {
      const float dmv = ((const float*)&dmq[m])[r];
      const float adv = ((const float*)&adq[m])[r];
#pragma unroll
      for (int j = 0; j < 2; ++j) {
        const float hs = bf2f(((const unsigned short*)&hv[m][j])[r]);
        h[m][j][r] =
            fmaxf(fmaf(dmv, acc[m][j][r] + adv * hs, bias[j * 16 + l15]), 0.f);
      }
    }

  if (do_pool) {
#pragma unroll
    for (int j = 0; j < 2; ++j) {
      float v = fmaxf(fmaxf(h[0][j][0], h[0][j][1]),
                      fmaxf(h[0][j][2], h[0][j][3]));
      v = fmaxf(v, fmaxf(fmaxf(h[1][j][0], h[1][j][1]),
                         fmaxf(h[1][j][2], h[1][j][3])));
      v = fmaxf(v, __shfl_xor(v, 16, 64));
      v = fmaxf(v, __shfl_xor(v, 32, 64));
      if (q == 0)
        atomicMax(&gmax[b * HH + j * 16 + l15], __float_as_uint(v));
    }
  } else {
    // transpose h through LDS (overlays staging buf 0 — K-loop drained)
    float* hb = (float*)&smem[0][0];  // [32][33]
    __syncthreads();  // single wave: cheap; orders overlay reuse
#pragma unroll
    for (int m = 0; m < 2; ++m)
#pragma unroll
      for (int r = 0; r < 4; ++r) {
        const int row = m * 16 + q * 4 + r;
        hb[row * 33 + l15] = h[m][0][r];
        hb[row * 33 + 16 + l15] = h[m][1][r];
      }
    __syncthreads();
#pragma unroll
    for (int m = 0; m < 2; ++m) {
      unsigned short o0[4], o1[4];
#pragma unroll
      for (int r = 0; r < 4; ++r) {
        const int row = m * 16 + q * 4 + r;
        float s0 = 0.f, s1 = 0.f;
#pragma unroll
        for (int k = 0; k < HH; ++k) {
          const float hvv = hb[row * 33 + k];
          s0 = fmaf(hvv, Wn[k * HH + l15], s0);
          s1 = fmaf(hvv, Wn[k * HH + 16 + l15], s1);
        }
        const float dmv = ((const float*)&dmq[m])[r];
        o0[r] = (unsigned short)f2bf_rne(dmv * s0);
        o1[r] = (unsigned short)f2bf_rne(dmv * s1);
      }
      // rows m*16+q*4..+3 consecutive in hst_next's n-dim -> ushort4 stores
      *(ushort4*)(hst_next + ((size_t)b * HH + l15) * NN + mrow0 + m * 16 +
                  q * 4) = *(ushort4*)o0;
      *(ushort4*)(hst_next + ((size_t)b * HH + 16 + l15) * NN + mrow0 +
                  m * 16 + q * 4) = *(ushort4*)o1;
    }
  }
}

// out[b] = (relu(g @ Wf1 + bf1)) @ Wf2 + bf2 ; one wave per batch
__global__ __launch_bounds__(64) void head_kernel(const unsigned int* __restrict__ gmax,
                                                  const float* __restrict__ Wf1,
                                                  const float* __restrict__ bf1,
                                                  const float* __restrict__ Wf2,
                                                  const float* __restrict__ bf2,
                                                  float* __restrict__ out) {
  const int b = blockIdx.x;
  const int t = threadIdx.x;  // 0..63 hidden units
  float acc = bf1[t];
#pragma unroll
  for (int c = 0; c < HH; ++c)
    acc = fmaf(__uint_as_float(gmax[b * HH + c]), Wf1[c * (2 * HH) + t], acc);
  acc = fmaxf(acc, 0.f);
  float v = acc * Wf2[t];
  v = warp_sum64(v);
  if (t == 0) out[b] = v + bf2[0];
}

extern "C" void kernel_launch(void* const* d_in, const int* in_sizes, int n_in,
                              void* d_out, int out_size, void* d_ws, size_t ws_size,
                              hipStream_t stream) {
  const float* x   = (const float*)d_in[0];
  const float* a   = (const float*)d_in[1];
  const float* W1  = (const float*)d_in[2];
  const float* b1  = (const float*)d_in[3];
  const float* W2  = (const float*)d_in[4];
  const float* b2  = (const float*)d_in[5];
  const float* W3  = (const float*)d_in[6];
  const float* b3  = (const float*)d_in[7];
  const float* Wf1 = (const float*)d_in[8];
  const float* bf1 = (const float*)d_in[9];
  const float* Wf2 = (const float*)d_in[10];
  const float* bf2 = (const float*)d_in[11];
  float* out = (float*)d_out;

  float* ws = (float*)d_ws;
  const size_t BN = (size_t)BB * NN;  // 16384
  float* dm   = ws;                                       // 16384 f
  float* addf = dm + BN;                                  // 16384 f
  unsigned int* gmax = (unsigned int*)(addf + BN);        // 256 u32
  unsigned short* hst_a = (unsigned short*)(gmax + 256);  // 1 MB
  unsigned short* hst_b = hst_a + BN * HH;                // 1 MB
  unsigned short* Abf = hst_b + BN * HH;                  // 67 MB bf16 A
  // total ws use ~69.5 MB

  deg_cvt_xw_kernel<<<BN / 4, 256, 0, stream>>>(a, x, W1, dm, addf, Abf, hst_a,
                                                gmax);

  layer_kernel<<<BB * 64, 64, 0, stream>>>(Abf, hst_a, dm, addf, b1, W2,
                                           hst_b, nullptr, 0);
  layer_kernel<<<BB * 64, 64, 0, stream>>>(Abf, hst_b, dm, addf, b2, W3,
                                           hst_a, nullptr, 0);
  layer_kernel<<<BB * 64, 64, 0, stream>>>(Abf, hst_a, dm, addf, b3, nullptr,
                                           nullptr, gmax, 1);

  head_kernel<<<BB, 64, 0, stream>>>(gmax, Wf1, bf1, Wf2, bf2, out);
}